// Round 2
// baseline (715.582 us; speedup 1.0000x reference)
//
#include <hip/hip_runtime.h>

// Depthwise cross-correlation, B*C = 32768 independent planes:
//   x[32][32] (*) k[8][8] -> out[25][25]
// softmax(weight) sums to exactly 1.0 -> output == correlation; weight unused.
//
// Decomposition: thread = (plane, 5x4 output tile). 35 threads/plane
// (5 row-groups x 7 col-groups; col-group 6 has 1 valid col).
// x staged in LDS with row stride 36 dwords (36%32=4 de-aliases banks,
// 16B-aligned, and absorbs the col-group-6 overrun). Kernel taps are
// loaded directly from global (L1 broadcast) to keep the LDS pipe for x.

#define NPLANES (128 * 256)
#define PPB 7                 // planes per block
#define RS  36                // LDS row stride (dwords)
#define PSD (32 * RS + 4)     // 1156 dwords plane stride; %32==4, %4==0
#define OH 25
#define OW 25

__global__ __launch_bounds__(256, 4)
void dwxcorr_kernel(const float* __restrict__ x,
                    const float* __restrict__ kern,
                    float* __restrict__ out) {
    __shared__ float lds[PPB * PSD];   // 32368 B -> 4-5 blocks/CU
    const int tid = threadIdx.x;
    const int plane0 = blockIdx.x * PPB;
    const int nplane = (NPLANES - plane0 < PPB) ? (NPLANES - plane0) : PPB;

    // ---- Stage x: nplane*256 float4, coalesced, 16B-aligned LDS writes ----
    const int nf4 = nplane * 256;
    for (int idx = tid; idx < nf4; idx += 256) {
        const int pb  = idx >> 8;        // 256 float4 per plane
        const int o4  = idx & 255;
        const int row = o4 >> 3;         // 8 float4 per row
        const int c4  = o4 & 7;
        const float4 v =
            reinterpret_cast<const float4*>(x)[(size_t)(plane0 + pb) * 256 + o4];
        *reinterpret_cast<float4*>(&lds[pb * PSD + row * RS + c4 * 4]) = v;
    }
    __syncthreads();

    const int pb = tid / 35;
    if (pb >= nplane) return;            // tids 245..255 idle (+ tail block)
    const int t  = tid % 35;
    const int rg = t / 7;                // output rows rg*5 .. rg*5+4
    const int cg = t % 7;                // output cols cg*4 .. cg*4+3

    // ---- Kernel taps -> 64 regs, straight from global (broadcast, L1-hit) ----
    float kk[64];
    {
        const float4* kp =
            reinterpret_cast<const float4*>(kern) + (size_t)(plane0 + pb) * 16;
#pragma unroll
        for (int i = 0; i < 16; ++i) {
            const float4 v = kp[i];
            kk[4 * i + 0] = v.x; kk[4 * i + 1] = v.y;
            kk[4 * i + 2] = v.z; kk[4 * i + 3] = v.w;
        }
    }

    float acc[5][4];
#pragma unroll
    for (int i = 0; i < 5; ++i)
#pragma unroll
        for (int j = 0; j < 4; ++j) acc[i][j] = 0.f;

    // ---- Compute: 12 x-rows, 3 aligned b128 LDS reads each ----
    const float* xp = &lds[pb * PSD + cg * 4];
#pragma unroll
    for (int ar = 0; ar < 12; ++ar) {
        const int row = rg * 5 + ar;     // 0..31
        const float* rp = xp + row * RS;
        float xr[12];
#pragma unroll
        for (int j = 0; j < 3; ++j) {
            const float4 v = *reinterpret_cast<const float4*>(rp + 4 * j);
            xr[4 * j + 0] = v.x; xr[4 * j + 1] = v.y;
            xr[4 * j + 2] = v.z; xr[4 * j + 3] = v.w;
        }
#pragma unroll
        for (int ky = 0; ky < 8; ++ky) {
            const int oy = ar - ky;      // compile-time with full unroll
            if (oy >= 0 && oy < 5) {
#pragma unroll
                for (int kx = 0; kx < 8; ++kx) {
                    const float kv = kk[ky * 8 + kx];
#pragma unroll
                    for (int oc = 0; oc < 4; ++oc)
                        acc[oy][oc] = fmaf(xr[kx + oc], kv, acc[oy][oc]);
                }
            }
        }
    }

    // ---- Store 5x4 tile (col 25..27 of col-group 6 dropped) ----
    float* op = out + (size_t)(plane0 + pb) * (OH * OW);
#pragma unroll
    for (int oy = 0; oy < 5; ++oy) {
        const int orow = rg * 5 + oy;
#pragma unroll
        for (int oc = 0; oc < 4; ++oc) {
            const int col = cg * 4 + oc;
            if (col < OW) op[orow * OW + col] = acc[oy][oc];
        }
    }
}

extern "C" void kernel_launch(void* const* d_in, const int* in_sizes, int n_in,
                              void* d_out, int out_size, void* d_ws, size_t ws_size,
                              hipStream_t stream) {
    const float* x = (const float*)d_in[0];
    const float* k = (const float*)d_in[1];
    // d_in[2] (weight) unused: softmax weights sum to exactly 1.
    float* out = (float*)d_out;
    const int nblocks = (NPLANES + PPB - 1) / PPB;   // 4682
    dwxcorr_kernel<<<nblocks, 256, 0, stream>>>(x, k, out);
}

// Round 3
// 72.287 us; speedup vs baseline: 9.8992x; 9.8992x over previous
//
#include <hip/hip_runtime.h>

// Depthwise cross-correlation, B*C = 32768 independent planes:
//   x[32][32] (*) k[8][8] -> out[25][25]
// softmax(weight) sums to exactly 1.0 -> output == correlation; weight unused.
//
// Thread = (plane, 5x4 output tile); 35 threads/plane. x staged in LDS
// (row stride 36 dwords: 16B-aligned, de-aliases banks, absorbs col-group-6
// overrun). Kernel taps load from global (L1 broadcast) in TWO ky-halves of
// 32 regs each -- round 2 kept all 64 in regs and the allocator spilled them
// to scratch (FETCH 1.8GB, VALUBusy 6%). Register demand now ~70.

#define NPLANES (128 * 256)
#define PPB 7                 // planes per block
#define RS  36                // LDS row stride (dwords)
#define PSD (32 * RS + 4)     // 1156 dwords plane stride
#define OH 25
#define OW 25

__global__ __launch_bounds__(256)   // no min-waves: let allocator use ~90 VGPRs, no spill
void dwxcorr_kernel(const float* __restrict__ x,
                    const float* __restrict__ kern,
                    float* __restrict__ out) {
    __shared__ float lds[PPB * PSD];   // 32368 B -> 5 blocks/CU max
    const int tid = threadIdx.x;
    const int plane0 = blockIdx.x * PPB;
    const int nplane = (NPLANES - plane0 < PPB) ? (NPLANES - plane0) : PPB;

    // ---- Stage x: nplane*256 float4, coalesced, 16B-aligned LDS writes ----
    const int nf4 = nplane * 256;
    for (int idx = tid; idx < nf4; idx += 256) {
        const int pb  = idx >> 8;        // 256 float4 per plane
        const int o4  = idx & 255;
        const int row = o4 >> 3;         // 8 float4 per row
        const int c4  = o4 & 7;
        const float4 v =
            reinterpret_cast<const float4*>(x)[(size_t)(plane0 + pb) * 256 + o4];
        *reinterpret_cast<float4*>(&lds[pb * PSD + row * RS + c4 * 4]) = v;
    }
    __syncthreads();

    const int pb = tid / 35;
    if (pb >= nplane) return;            // tids 245..255 idle (+ tail block)
    const int t  = tid % 35;
    const int rg = t / 7;                // output rows rg*5 .. rg*5+4
    const int cg = t % 7;                // output cols cg*4 .. cg*4+3

    const float4* kp =
        reinterpret_cast<const float4*>(kern) + (size_t)(plane0 + pb) * 16;
    const float* xp = &lds[pb * PSD + cg * 4];

    float acc[5][4];
#pragma unroll
    for (int i = 0; i < 5; ++i)
#pragma unroll
        for (int j = 0; j < 4; ++j) acc[i][j] = 0.f;

    // ---- Two ky-halves: 32 taps in regs at a time, 8 x-rows each ----
#pragma unroll
    for (int h = 0; h < 2; ++h) {
        float kk[32];                    // taps ky = h*4 .. h*4+3
#pragma unroll
        for (int i = 0; i < 8; ++i) {
            const float4 v = kp[h * 8 + i];
            kk[4 * i + 0] = v.x; kk[4 * i + 1] = v.y;
            kk[4 * i + 2] = v.z; kk[4 * i + 3] = v.w;
        }
#pragma unroll
        for (int a = 0; a < 8; ++a) {
            const int row = rg * 5 + h * 4 + a;   // 0..31
            const float* rp = xp + row * RS;
            float xr[12];
#pragma unroll
            for (int j = 0; j < 3; ++j) {
                const float4 v = *reinterpret_cast<const float4*>(rp + 4 * j);
                xr[4 * j + 0] = v.x; xr[4 * j + 1] = v.y;
                xr[4 * j + 2] = v.z; xr[4 * j + 3] = v.w;
            }
#pragma unroll
            for (int kyl = 0; kyl < 4; ++kyl) {
                const int oy = a - kyl;           // compile-time
                if (oy >= 0 && oy < 5) {
#pragma unroll
                    for (int kx = 0; kx < 8; ++kx) {
                        const float kv = kk[kyl * 8 + kx];
#pragma unroll
                        for (int oc = 0; oc < 4; ++oc)
                            acc[oy][oc] = fmaf(xr[kx + oc], kv, acc[oy][oc]);
                    }
                }
            }
        }
    }

    // ---- Store 5x4 tile (cols 25..27 of col-group 6 dropped) ----
    float* op = out + (size_t)(plane0 + pb) * (OH * OW);
#pragma unroll
    for (int oy = 0; oy < 5; ++oy) {
        const int orow = rg * 5 + oy;
#pragma unroll
        for (int oc = 0; oc < 4; ++oc) {
            const int col = cg * 4 + oc;
            if (col < OW) op[orow * OW + col] = acc[oy][oc];
        }
    }
}

extern "C" void kernel_launch(void* const* d_in, const int* in_sizes, int n_in,
                              void* d_out, int out_size, void* d_ws, size_t ws_size,
                              hipStream_t stream) {
    const float* x = (const float*)d_in[0];
    const float* k = (const float*)d_in[1];
    // d_in[2] (weight) unused: softmax weights sum to exactly 1.
    float* out = (float*)d_out;
    const int nblocks = (NPLANES + PPB - 1) / PPB;   // 4682
    dwxcorr_kernel<<<nblocks, 256, 0, stream>>>(x, k, out);
}